// Round 1
// baseline (97.667 us; speedup 1.0000x reference)
//
#include <hip/hip_runtime.h>
#include <math.h>

#define N_PTS 4096
#define RPW 2              // rows per wave
#define WPB 4              // waves per block
#define BLOCK (WPB * 64)

// Kernel 1: pack pos/vel into float4 per point, reduce velocity sum for group_vel.
__global__ void prep_kernel(const float* __restrict__ states,
                            float4* __restrict__ pv,
                            float* __restrict__ vsum) {
    int j = blockIdx.x * blockDim.x + threadIdx.x;
    const float4 s0 = *reinterpret_cast<const float4*>(states + j * 8);
    const float4 s1 = *reinterpret_cast<const float4*>(states + j * 8 + 4);
    float px = (s0.x + s0.z) * 0.5f;
    float py = (s0.y + s0.w) * 0.5f;
    float vx = (s1.x + s1.z) * 0.5f;
    float vy = (s1.y + s1.w) * 0.5f;
    pv[j] = make_float4(px, py, vx, vy);

    // wave-level reduction of velocity sums, one atomic per wave
    float sx = vx, sy = vy;
    #pragma unroll
    for (int off = 32; off; off >>= 1) {
        sx += __shfl_down(sx, off);
        sy += __shfl_down(sy, off);
    }
    if ((threadIdx.x & 63) == 0) {
        atomicAdd(vsum + 0, sx);
        atomicAdd(vsum + 1, sy);
    }
}

// Kernel 2: per-row online-softmax aggregation. One wave handles RPW rows.
__global__ __launch_bounds__(BLOCK) void agg_kernel(
        const float4* __restrict__ pv,
        const float* __restrict__ vsum,
        const float* __restrict__ log_tau_p,
        float* __restrict__ out) {
    const int lane = threadIdx.x & 63;
    const int wave = threadIdx.x >> 6;
    const int gwave = blockIdx.x * WPB + wave;
    const int row0 = gwave * RPW;

    const float inv_tau = __expf(-log_tau_p[0]);     // 1/tau
    const float gvx = vsum[0] * (1.0f / N_PTS);
    const float gvy = vsum[1] * (1.0f / N_PTS);

    float4 pi[RPW];
    #pragma unroll
    for (int r = 0; r < RPW; ++r) pi[r] = pv[row0 + r];

    float m[RPW], l[RPW], S1[RPW][4], S2[RPW][4];
    #pragma unroll
    for (int r = 0; r < RPW; ++r) {
        m[r] = -INFINITY;
        l[r] = 0.0f;
        #pragma unroll
        for (int d = 0; d < 4; ++d) { S1[r][d] = 0.0f; S2[r][d] = 0.0f; }
    }

    #pragma unroll 2
    for (int j = lane; j < N_PTS; j += 64) {
        const float4 q = pv[j];
        #pragma unroll
        for (int r = 0; r < RPW; ++r) {
            float dx  = pi[r].x - q.x;
            float dy  = pi[r].y - q.y;
            float dvx = pi[r].z - q.z;
            float dvy = pi[r].w - q.w;
            float d2   = fmaf(dy, dy, fmaf(dx, dx, 1e-8f));
            float dist = sqrtf(d2);
            float logit = dist * (-inv_tau);
            if (j != row0 + r) {
                if (logit <= m[r]) {
                    // common path: no new max
                    float w = __expf(logit - m[r]);
                    l[r] += w;
                    float t0 = w * dx;
                    float t1 = w * dy;
                    float t2 = w * dvx;
                    float t3 = w * dvy;
                    S1[r][0] += t0; S2[r][0] = fmaf(t0, dx,  S2[r][0]);
                    S1[r][1] += t1; S2[r][1] = fmaf(t1, dy,  S2[r][1]);
                    S1[r][2] += t2; S2[r][2] = fmaf(t2, dvx, S2[r][2]);
                    S1[r][3] += t3; S2[r][3] = fmaf(t3, dvy, S2[r][3]);
                } else {
                    // new max: rescale old state, current weight = 1
                    float s = __expf(m[r] - logit);   // exp(-inf)=0 handles init
                    m[r] = logit;
                    l[r] = fmaf(l[r], s, 1.0f);
                    S1[r][0] = fmaf(S1[r][0], s, dx);
                    S1[r][1] = fmaf(S1[r][1], s, dy);
                    S1[r][2] = fmaf(S1[r][2], s, dvx);
                    S1[r][3] = fmaf(S1[r][3], s, dvy);
                    S2[r][0] = fmaf(S2[r][0], s, dx * dx);
                    S2[r][1] = fmaf(S2[r][1], s, dy * dy);
                    S2[r][2] = fmaf(S2[r][2], s, dvx * dvx);
                    S2[r][3] = fmaf(S2[r][3], s, dvy * dvy);
                }
            }
        }
    }

    // 64-lane butterfly merge of (m, l, S1, S2) with max-rescale
    #pragma unroll
    for (int r = 0; r < RPW; ++r) {
        for (int off = 32; off; off >>= 1) {
            float m2 = __shfl_xor(m[r], off);
            float l2 = __shfl_xor(l[r], off);
            float t1[4], t2[4];
            #pragma unroll
            for (int d = 0; d < 4; ++d) {
                t1[d] = __shfl_xor(S1[r][d], off);
                t2[d] = __shfl_xor(S2[r][d], off);
            }
            float M = fmaxf(m[r], m2);
            float a = __expf(m[r] - M);
            float b = __expf(m2 - M);
            l[r] = fmaf(l2, b, l[r] * a);
            #pragma unroll
            for (int d = 0; d < 4; ++d) {
                S1[r][d] = fmaf(t1[d], b, S1[r][d] * a);
                S2[r][d] = fmaf(t2[d], b, S2[r][d] * a);
            }
            m[r] = M;
        }
        if (lane == 0) {
            const float inv_l = 1.0f / l[r];
            float mu[4], sg[4];
            #pragma unroll
            for (int d = 0; d < 4; ++d) mu[d] = S1[r][d] * inv_l;
            #pragma unroll
            for (int d = 0; d < 4; ++d) {
                float v = fmaf(-mu[d], mu[d], S2[r][d] * inv_l);
                sg[d] = sqrtf(v + 1e-6f);
            }
            const int i = row0 + r;
            float4* o = reinterpret_cast<float4*>(out + i * 12);
            o[0] = make_float4(mu[0], mu[1], mu[2], mu[3]);
            o[1] = make_float4(sg[0], sg[1], sg[2], sg[3]);
            o[2] = make_float4(gvx, gvy, pi[r].z - gvx, pi[r].w - gvy);
        }
    }
}

extern "C" void kernel_launch(void* const* d_in, const int* in_sizes, int n_in,
                              void* d_out, int out_size, void* d_ws, size_t ws_size,
                              hipStream_t stream) {
    const float* states  = (const float*)d_in[0];
    const float* log_tau = (const float*)d_in[1];
    float* out = (float*)d_out;

    float*  vsum = (float*)d_ws;                       // 2 floats (zeroed below)
    float4* pv   = (float4*)((char*)d_ws + 256);       // 64 KB packed pos/vel

    hipMemsetAsync(d_ws, 0, 256, stream);
    prep_kernel<<<N_PTS / 256, 256, 0, stream>>>(states, pv, vsum);
    agg_kernel<<<N_PTS / (RPW * WPB), BLOCK, 0, stream>>>(pv, vsum, log_tau, out);
}

// Round 2
// 69.990 us; speedup vs baseline: 1.3954x; 1.3954x over previous
//
#include <hip/hip_runtime.h>
#include <math.h>

typedef float v2f __attribute__((ext_vector_type(2)));

#define N_PTS 4096
#define BLOCK 512            // 8 waves
#define RPB 4                // rows per block
#define SLICES (BLOCK / RPB) // 128 j-slices per block
#define JPS (N_PTS / SLICES) // 32 j's per slice

// One fused kernel: stage pv into LDS, per-block group_vel reduce, then
// per-(row,slice) online accumulation with fixed softmax shift m=0.
__global__ __launch_bounds__(BLOCK, 4) void fused_kernel(
        const float* __restrict__ states,
        const float* __restrict__ log_tau_p,
        float* __restrict__ out) {
    __shared__ float4 pv[N_PTS];        // 64 KB packed (pos.xy, vel.xy)
    __shared__ float wsum[8][2];        // per-wave vel sums
    __shared__ float red[8][RPB][10];   // cross-wave partial states

    const int tid  = threadIdx.x;
    const int lane = tid & 63;
    const int wave = tid >> 6;

    // exp(x) = exp2(x*log2e); fold -1/tau and log2e into one constant
    const float c = -__expf(-log_tau_p[0]) * 1.4426950408889634f;

    // ---- Stage: compute pv for all 4096 points; accumulate vel sums ----
    float svx = 0.f, svy = 0.f;
    #pragma unroll
    for (int k = 0; k < N_PTS / BLOCK; ++k) {
        const int p = tid + k * BLOCK;
        const float4 s0 = *reinterpret_cast<const float4*>(states + p * 8);
        const float4 s1 = *reinterpret_cast<const float4*>(states + p * 8 + 4);
        float4 e;
        e.x = (s0.x + s0.z) * 0.5f;
        e.y = (s0.y + s0.w) * 0.5f;
        e.z = (s1.x + s1.z) * 0.5f;
        e.w = (s1.y + s1.w) * 0.5f;
        pv[p] = e;
        svx += e.z; svy += e.w;
    }
    #pragma unroll
    for (int off = 32; off; off >>= 1) {
        svx += __shfl_down(svx, off);
        svy += __shfl_down(svy, off);
    }
    if (lane == 0) { wsum[wave][0] = svx; wsum[wave][1] = svy; }
    __syncthreads();   // pv + wsum ready

    // ---- Main loop: lane owns (row = lane&3, slice = wave*16 + lane>>2) ----
    const int rowg  = blockIdx.x * RPB + (lane & 3);
    const int slice = wave * (SLICES / 8) + (lane >> 2);
    const float4 pi = pv[rowg];

    float l = 0.f;
    v2f S1p = {0.f, 0.f}, S1v = {0.f, 0.f}, S2p = {0.f, 0.f}, S2v = {0.f, 0.f};

    #pragma unroll 8
    for (int tt = 0; tt < JPS; ++tt) {
        const float4 q = pv[slice + tt * SLICES];
        v2f dp = {pi.x - q.x, pi.y - q.y};
        v2f dv = {pi.z - q.z, pi.w - q.w};
        v2f p2 = dp * dp;
        float d2 = p2.x + p2.y + 1e-8f;
        float dist = __builtin_amdgcn_sqrtf(d2);
        float w = __builtin_amdgcn_exp2f(dist * c);
        l += w;
        v2f wv = {w, w};
        S1p += dp * wv;
        S1v += dv * wv;
        S2p += p2 * wv;
        S2v += (dv * dv) * wv;
    }

    // ---- In-wave merge over 16 slices (lanes stride 4): pure adds ----
    #pragma unroll
    for (int off = 4; off < 64; off <<= 1) {
        l     += __shfl_xor(l, off);
        S1p.x += __shfl_xor(S1p.x, off);
        S1p.y += __shfl_xor(S1p.y, off);
        S1v.x += __shfl_xor(S1v.x, off);
        S1v.y += __shfl_xor(S1v.y, off);
        S2p.x += __shfl_xor(S2p.x, off);
        S2p.y += __shfl_xor(S2p.y, off);
        S2v.x += __shfl_xor(S2v.x, off);
        S2v.y += __shfl_xor(S2v.y, off);
    }
    if (lane < RPB) {
        float* rr = red[wave][lane];
        rr[0] = l;
        rr[1] = S1p.x; rr[2] = S1p.y; rr[3] = S1v.x; rr[4] = S1v.y;
        rr[5] = S2p.x; rr[6] = S2p.y; rr[7] = S2v.x; rr[8] = S2v.y;
    }
    __syncthreads();

    // ---- Finalize: 4 threads, one row each ----
    if (tid < RPB) {
        float acc[9];
        #pragma unroll
        for (int cc = 0; cc < 9; ++cc) acc[cc] = red[0][tid][cc];
        #pragma unroll
        for (int wv = 1; wv < 8; ++wv)
            #pragma unroll
            for (int cc = 0; cc < 9; ++cc) acc[cc] += red[wv][tid][cc];

        // subtract the diagonal's weight (identical float path as in-loop)
        const float w_diag = __builtin_amdgcn_exp2f(__builtin_amdgcn_sqrtf(1e-8f) * c);
        const float inv_l = 1.0f / (acc[0] - w_diag);

        float gvx = 0.f, gvy = 0.f;
        #pragma unroll
        for (int wv = 0; wv < 8; ++wv) { gvx += wsum[wv][0]; gvy += wsum[wv][1]; }
        gvx *= (1.0f / N_PTS);
        gvy *= (1.0f / N_PTS);

        const int row = blockIdx.x * RPB + tid;
        const float4 pr = pv[row];

        float mu[4], sg[4];
        #pragma unroll
        for (int d = 0; d < 4; ++d) mu[d] = acc[1 + d] * inv_l;
        #pragma unroll
        for (int d = 0; d < 4; ++d) {
            float v = fmaf(-mu[d], mu[d], acc[5 + d] * inv_l);
            sg[d] = __builtin_amdgcn_sqrtf(v + 1e-6f);
        }
        float4* o = reinterpret_cast<float4*>(out + row * 12);
        o[0] = make_float4(mu[0], mu[1], mu[2], mu[3]);
        o[1] = make_float4(sg[0], sg[1], sg[2], sg[3]);
        o[2] = make_float4(gvx, gvy, pr.z - gvx, pr.w - gvy);
    }
}

extern "C" void kernel_launch(void* const* d_in, const int* in_sizes, int n_in,
                              void* d_out, int out_size, void* d_ws, size_t ws_size,
                              hipStream_t stream) {
    const float* states  = (const float*)d_in[0];
    const float* log_tau = (const float*)d_in[1];
    float* out = (float*)d_out;
    fused_kernel<<<N_PTS / RPB, BLOCK, 0, stream>>>(states, log_tau, out);
}